// Round 10
// baseline (218.112 us; speedup 1.0000x reference)
//
#include <hip/hip_runtime.h>
#include <type_traits>

// GCNEncoder: h1 = relu(SpMM(x@W0) + b0); h2 = relu(SpMM(h1@W1) + b1)
// mean = relu(h2@Wm1+bm1)@Wm2+bm2 ; logvar = relu(h2@Wv1+bv1)@Wv2+bv2
// R5: f16 pipeline, MFMA GEMMs. R7: block-local two-pass binning.
// R8: fused heads, fp32-A GEMM, half8 SpMM. R10: GEMM 2 A-frags/wave.
// R11 (FAILED +26): feature-chunked SpMM — line granularity + XCD replication.
// R12 (FAILED +11): bundled {unroll8, NT hints, fused build}.
// R13 (WIN -32.7, 218.9us): fused row-local GEMMs into spmm blocks.
// R14 (FAILED +13.7): degree-balanced rperm — serial tail + sort overhead.
// R15 (WIN -6.1, 212.8us): buildA || wconv; buildB || gemm-L1.
// R16 (FAILED +40.8): per-row col sort — no spmm gain (decoherence).
// R17 (FAILED +24.7): unroll8+NT gather — gather is L2-miss-BW-bound
//      (FETCH 88MB vs 19 ideal); spmm ~41us is near its structural floor.
// R18 (WIN -2.6, 210.2us): bscan fused into buildB; single-pass binning.
// R19: buildA scatter fix — CHUNK 4096 (halves blocks -> halves the 152K
//      bucket-reservation atomics; doubles run length to ~84B) + LDS
//      bucket-sort staging with LINEAR flush (consecutive threads write
//      consecutive bbuf slots per run) replacing the fully-random per-thread
//      8B scatter. Same staged-flush pattern bucketB already validates.

typedef _Float16 half8 __attribute__((ext_vector_type(8)));
typedef float floatx4 __attribute__((ext_vector_type(4)));

#define BCAP 2560   // bucket capacity; mean 2048, sigma ~45 -> +11 sigma
#define CHUNK 4096  // edges per binning block (R19: was 2048)
#define RB 128      // rows per bucket
#define NBKMAX 392  // bucket-count array size

// ---------------------------------------------------------------- gemm L1 (device)
// support1 = x(f32)@W0swz -> f16. R10 structure: 4 waves x 2 A-frags (32 rows),
// NT=8, KS=4. Wswz frag order [(ks*8+nt)*64+lane]*8+j, k=ks*32+quad*8+j,
// n=nt*16+(lane&15). C/D: col=lane&15, row=quad*4+reg (m89-verified).
__device__ void gemm_l1(int bid, const float* __restrict__ A,
                        const _Float16* __restrict__ Wswz,
                        _Float16* __restrict__ C0, int n) {
  const int t = threadIdx.x;
  const int lane = t & 63, wave = t >> 6;
  const int quad = lane >> 4, l16 = lane & 15;
  const int r_base = bid * 128 + wave * 32;

  int arow0 = r_base + l16;
  int arow1 = r_base + 16 + l16;
  if (arow0 >= n) arow0 = n - 1;        // clamp; clamped rows never stored
  if (arow1 >= n) arow1 = n - 1;
  const float* Ap0 = A + (size_t)arow0 * 128 + quad * 8;
  const float* Ap1 = A + (size_t)arow1 * 128 + quad * 8;

  floatx4 acc[2][8] = {};

#pragma unroll
  for (int ks = 0; ks < 4; ++ks) {
    float4 u = *(const float4*)(Ap0 + ks * 32);
    float4 w = *(const float4*)(Ap0 + ks * 32 + 4);
    half8 a0 = half8{(_Float16)u.x, (_Float16)u.y, (_Float16)u.z, (_Float16)u.w,
                     (_Float16)w.x, (_Float16)w.y, (_Float16)w.z, (_Float16)w.w};
    float4 u1 = *(const float4*)(Ap1 + ks * 32);
    float4 w1 = *(const float4*)(Ap1 + ks * 32 + 4);
    half8 a1 = half8{(_Float16)u1.x, (_Float16)u1.y, (_Float16)u1.z, (_Float16)u1.w,
                     (_Float16)w1.x, (_Float16)w1.y, (_Float16)w1.z, (_Float16)w1.w};
#pragma unroll
    for (int nt = 0; nt < 8; ++nt) {
      half8 b = *(const half8*)(Wswz + ((size_t)(ks * 8 + nt) * 64 + lane) * 8);
      acc[0][nt] = __builtin_amdgcn_mfma_f32_16x16x32_f16(a0, b, acc[0][nt], 0, 0, 0);
      acc[1][nt] = __builtin_amdgcn_mfma_f32_16x16x32_f16(a1, b, acc[1][nt], 0, 0, 0);
    }
  }

#pragma unroll
  for (int h = 0; h < 2; ++h) {
#pragma unroll
    for (int nt = 0; nt < 8; ++nt) {
      const int col = nt * 16 + l16;
#pragma unroll
      for (int r = 0; r < 4; ++r) {
        int row = r_base + h * 16 + quad * 4 + r;
        if (row < n) C0[(size_t)row * 128 + col] = (_Float16)acc[h][nt][r];
      }
    }
  }
}

// ---------------------------------------------------------------- buildA
// Blocks [0, binBlocks): block-local binning with LDS bucket-sort staging
// and linear (runwise-coalesced) flush to bbuf.
// Blocks [binBlocks, binBlocks+256): weight swizzle (4 segs).
__global__ __launch_bounds__(256)
void buildA_kernel(const int* __restrict__ rows, const int* __restrict__ cols,
                   const float* __restrict__ vals,
                   int* __restrict__ bcur, uint2* __restrict__ bbuf, int e,
                   int binBlocks,
                   const float* __restrict__ w0, const float* __restrict__ w1,
                   const float* __restrict__ wm1, const float* __restrict__ wv1,
                   const float* __restrict__ wm2, const float* __restrict__ wv2,
                   _Float16* __restrict__ d0, _Float16* __restrict__ d1,
                   _Float16* __restrict__ dh1, _Float16* __restrict__ dh2) {
  __shared__ int cnt[NBKMAX];
  __shared__ int excl[NBKMAX];
  __shared__ int lcur[NBKMAX];
  __shared__ int gbase[NBKMAX];
  __shared__ int sc[512];
  __shared__ uint2 stage[CHUNK];      // 32 KB
  const int t = threadIdx.x;

  if (blockIdx.x >= binBlocks) {
    // ---- weight conversion (swizzle to MFMA fragment order)
    int i = (blockIdx.x - binBlocks) * 256 + t;
    if (i >= 65536) return;
    int seg = i >> 14, li = i & 16383;
    int j = li & 7, lane = (li >> 3) & 63, tt = li >> 9;
    int nt = tt & 7, ks = tt >> 3;         // NT=8, KS=4
    int k = ks * 32 + (lane >> 4) * 8 + j;
    int nn = nt * 16 + (lane & 15);
    float v;
    if (seg == 0)      v = w0[k * 128 + nn];
    else if (seg == 1) v = w1[k * 128 + nn];
    else if (seg == 2) v = (nn < 64) ? wm1[k * 64 + nn] : wv1[k * 64 + (nn - 64)];
    else v = (k < 64 && nn < 64) ? wm2[k * 64 + nn]
           : (k >= 64 && nn >= 64) ? wv2[(k - 64) * 64 + (nn - 64)] : 0.f;
    _Float16* dst = (seg == 0) ? d0 : (seg == 1) ? d1 : (seg == 2) ? dh1 : dh2;
    dst[li] = (_Float16)v;
    return;
  }

  // ---- binning: hist -> scan -> reserve -> LDS bucket-sort -> linear flush
  const int lo = blockIdx.x * CHUNK, hi = min(lo + CHUNK, e);
  for (int j = t; j < NBKMAX; j += 256) cnt[j] = 0;
  __syncthreads();
  for (int i = lo + t; i < hi; i += 256)
    atomicAdd(&cnt[rows[i] >> 7], 1);
  __syncthreads();
  // inclusive scan over 512-padded cnt (Hillis-Steele, 2 elems/thread)
  sc[t] = (t < NBKMAX) ? cnt[t] : 0;
  sc[t + 256] = (t + 256 < NBKMAX) ? cnt[t + 256] : 0;
  __syncthreads();
#pragma unroll
  for (int off = 1; off < 512; off <<= 1) {
    int a0 = (t >= off) ? sc[t - off] : 0;
    int a1 = (t + 256 >= off) ? sc[t + 256 - off] : 0;
    __syncthreads();
    sc[t] += a0;
    sc[t + 256] += a1;
    __syncthreads();
  }
  for (int j = t; j < NBKMAX; j += 256) {
    int ex = sc[j] - cnt[j];
    excl[j] = ex;
    lcur[j] = ex;
    if (cnt[j] > 0) gbase[j] = atomicAdd(&bcur[j * 16], cnt[j]);
  }
  __syncthreads();
  // stage edges bucket-ordered in LDS (2nd edge read is L2-warm)
  for (int i = lo + t; i < hi; i += 256) {
    int r = rows[i];
    int p = atomicAdd(&lcur[r >> 7], 1);
    stage[p] = make_uint2(((unsigned)r << 16) | (unsigned)cols[i],
                          __float_as_uint(vals[i]));
  }
  __syncthreads();
  // linear flush: consecutive i -> consecutive slots within each bucket run
  const int tot = hi - lo;
  for (int i = t; i < tot; i += 256) {
    uint2 u = stage[i];
    int b = (int)(u.x >> 16) >> 7;
    int slot = gbase[b] + (i - excl[b]);
    if (slot < BCAP)
      bbuf[(size_t)b * BCAP + slot] = make_uint2(u.x & 0x007FFFFFu, u.y);
  }
}

// ---------------------------------------------------------------- buildB
// Blocks [0, nbk): bucketB — fused bucket-base prefix (over bcur), per-bucket
// LDS hist+scan -> row_ptr; LDS-staged coalesced CSR flush (~22.5 KB LDS).
// Blocks [nbk, nbk+GB): gemm_l1 — support1 = x@W0 (independent; overlaps).
__global__ __launch_bounds__(256)
void buildB_kernel(const uint2* __restrict__ bbuf, const int* __restrict__ bcur,
                   int* __restrict__ row_ptr, int2* __restrict__ s_pack,
                   int nbk, int n, int e_total,
                   const float* __restrict__ x, const _Float16* __restrict__ W0s,
                   _Float16* __restrict__ sup) {
  __shared__ int cnt[RB];
  __shared__ int scn[RB];
  __shared__ int red[256];
  __shared__ int2 stage[BCAP];

  if (blockIdx.x >= nbk) {
    gemm_l1(blockIdx.x - nbk, x, W0s, sup, n);
    return;
  }

  const int b = blockIdx.x, t = threadIdx.x;

  // fused exclusive prefix over bucket counts (nbk <= 512 -> <=2 loads/thread)
  int partial = 0;
  for (int j = t; j < b; j += 256) partial += bcur[j * 16];
  red[t] = partial;
  __syncthreads();
#pragma unroll
  for (int off = 128; off > 0; off >>= 1) {
    if (t < off) red[t] += red[t + off];
    __syncthreads();
  }
  const int base = red[0];

  const int e = min(bcur[b * 16], BCAP);
  const uint2* src = bbuf + (size_t)b * BCAP;

  if (t < RB) cnt[t] = 0;
  __syncthreads();
  for (int i = t; i < e; i += 256)
    atomicAdd(&cnt[(src[i].x >> 16) & (RB - 1)], 1);
  __syncthreads();
  int c = (t < RB) ? cnt[t] : 0;
  if (t < RB) scn[t] = c;
  __syncthreads();
#pragma unroll
  for (int off = 1; off < RB; off <<= 1) {
    int a = (t >= off && t < RB) ? scn[t - off] : 0;
    __syncthreads();
    if (t < RB) scn[t] += a;
    __syncthreads();
  }
  if (t < RB) {
    int excl = scn[t] - c;
    int grow = b * RB + t;
    if (grow < n) row_ptr[grow] = base + excl;
    cnt[t] = excl;   // becomes per-row cursor
  }
  if (b == 0 && t == 0) row_ptr[n] = e_total;
  __syncthreads();
  for (int i = t; i < e; i += 256) {
    uint2 u = src[i];
    int pos = atomicAdd(&cnt[(u.x >> 16) & (RB - 1)], 1);
    stage[pos] = make_int2((int)(u.x & 0xFFFFu), (int)u.y);
  }
  __syncthreads();
  for (int i = t; i < e; i += 256)
    s_pack[base + i] = stage[i];
}

// ---------------------------------------------------------------- fused SpMM+GEMM
// Phase 1 (R10 gather core): 16 lanes/row, half8/lane, 16 rows/block,
// unroll 4, plain loads. h = relu(agg + gbias) -> LDS (padded 136) -> MFMA
// vs swizzled weights (A-frag pattern identical to gemm16, m89-verified).
// HEADS=false: emit support2 = h@W1swz. HEADS=true: t = relu(h@W1swz+[hb]),
// out = t@W2swz+[ob], split fp32 stores.
template<bool HEADS>
__global__ __launch_bounds__(256)
void spmm_fused(const half8* __restrict__ sup, const int* __restrict__ row_ptr,
                const int2* __restrict__ s_pack, const float* __restrict__ gbias,
                const _Float16* __restrict__ W1swz, const _Float16* __restrict__ W2swz,
                const float* __restrict__ hb0, const float* __restrict__ hb1,
                const float* __restrict__ ob0, const float* __restrict__ ob1,
                _Float16* __restrict__ outA, float* __restrict__ outM,
                float* __restrict__ outV, int n) {
  __shared__ _Float16 hs[16][136];
  __shared__ _Float16 ts[HEADS ? 16 : 1][136];
  const int t = threadIdx.x;
  const int g = t >> 4;
  const int l = t & 15;                 // feats [8l, 8l+8)
  int r = blockIdx.x * 16 + g;
  if (r >= n) r = n - 1;                // N%16==0 in practice; stores guarded
  const int beg = row_ptr[r], end = row_ptr[r + 1];

  // ---- gather
  float acc[8] = {};
  int i = beg;
  for (; i + 3 < end; i += 4) {
    int2 e0 = s_pack[i], e1 = s_pack[i + 1], e2 = s_pack[i + 2], e3 = s_pack[i + 3];
    half8 g0 = sup[(size_t)e0.x * 16 + l];
    half8 g1 = sup[(size_t)e1.x * 16 + l];
    half8 g2 = sup[(size_t)e2.x * 16 + l];
    half8 g3 = sup[(size_t)e3.x * 16 + l];
    float v0 = __int_as_float(e0.y), v1 = __int_as_float(e1.y);
    float v2 = __int_as_float(e2.y), v3 = __int_as_float(e3.y);
#pragma unroll
    for (int jj = 0; jj < 8; ++jj) acc[jj] = fmaf(v0, (float)g0[jj], acc[jj]);
#pragma unroll
    for (int jj = 0; jj < 8; ++jj) acc[jj] = fmaf(v1, (float)g1[jj], acc[jj]);
#pragma unroll
    for (int jj = 0; jj < 8; ++jj) acc[jj] = fmaf(v2, (float)g2[jj], acc[jj]);
#pragma unroll
    for (int jj = 0; jj < 8; ++jj) acc[jj] = fmaf(v3, (float)g3[jj], acc[jj]);
  }
  for (; i < end; ++i) {
    int2 e0 = s_pack[i];
    float v = __int_as_float(e0.y);
    half8 gg = sup[(size_t)e0.x * 16 + l];
#pragma unroll
    for (int jj = 0; jj < 8; ++jj) acc[jj] = fmaf(v, (float)gg[jj], acc[jj]);
  }

  // ---- h = relu(acc + gbias) -> LDS tile
  float4 b0 = *(const float4*)(gbias + 8 * l);
  float4 b1 = *(const float4*)(gbias + 8 * l + 4);
  _Float16* hp = &hs[g][8 * l];
  hp[0] = (_Float16)fmaxf(acc[0] + b0.x, 0.f);
  hp[1] = (_Float16)fmaxf(acc[1] + b0.y, 0.f);
  hp[2] = (_Float16)fmaxf(acc[2] + b0.z, 0.f);
  hp[3] = (_Float16)fmaxf(acc[3] + b0.w, 0.f);
  hp[4] = (_Float16)fmaxf(acc[4] + b1.x, 0.f);
  hp[5] = (_Float16)fmaxf(acc[5] + b1.y, 0.f);
  hp[6] = (_Float16)fmaxf(acc[6] + b1.z, 0.f);
  hp[7] = (_Float16)fmaxf(acc[7] + b1.w, 0.f);
  __syncthreads();

  // ---- MFMA phase: wave handles cols [wave*32, wave*32+32)
  const int lane = t & 63, wave = t >> 6;
  const int quad = lane >> 4, l16 = lane & 15;
  floatx4 cacc[2] = {{0.f, 0.f, 0.f, 0.f}, {0.f, 0.f, 0.f, 0.f}};
#pragma unroll
  for (int ks = 0; ks < 4; ++ks) {
    half8 a = *(const half8*)&hs[l16][ks * 32 + quad * 8];
#pragma unroll
    for (int nt = 0; nt < 2; ++nt) {
      int ntg = wave * 2 + nt;
      half8 b = *(const half8*)(W1swz + ((size_t)(ks * 8 + ntg) * 64 + lane) * 8);
      cacc[nt] = __builtin_amdgcn_mfma_f32_16x16x32_f16(a, b, cacc[nt], 0, 0, 0);
    }
  }

  if constexpr (!HEADS) {
#pragma unroll
    for (int nt = 0; nt < 2; ++nt) {
      int col = wave * 32 + nt * 16 + l16;
#pragma unroll
      for (int rr = 0; rr < 4; ++rr) {
        int row = blockIdx.x * 16 + quad * 4 + rr;
        if (row < n) outA[(size_t)row * 128 + col] = (_Float16)cacc[nt][rr];
      }
    }
  } else {
#pragma unroll
    for (int nt = 0; nt < 2; ++nt) {
      int col = wave * 32 + nt * 16 + l16;
      float bv = (col < 64) ? hb0[col] : hb1[col - 64];
#pragma unroll
      for (int rr = 0; rr < 4; ++rr)
        ts[quad * 4 + rr][col] = (_Float16)fmaxf(cacc[nt][rr] + bv, 0.f);
    }
    __syncthreads();
    floatx4 oacc[2] = {{0.f, 0.f, 0.f, 0.f}, {0.f, 0.f, 0.f, 0.f}};
#pragma unroll
    for (int ks = 0; ks < 4; ++ks) {
      half8 a = *(const half8*)&ts[l16][ks * 32 + quad * 8];
#pragma unroll
      for (int nt = 0; nt < 2; ++nt) {
        int ntg = wave * 2 + nt;
        half8 b = *(const half8*)(W2swz + ((size_t)(ks * 8 + ntg) * 64 + lane) * 8);
        oacc[nt] = __builtin_amdgcn_mfma_f32_16x16x32_f16(a, b, oacc[nt], 0, 0, 0);
      }
    }
#pragma unroll
    for (int nt = 0; nt < 2; ++nt) {
      int col = wave * 32 + nt * 16 + l16;
      float bv = (col < 64) ? ob0[col] : ob1[col - 64];
#pragma unroll
      for (int rr = 0; rr < 4; ++rr) {
        int row = blockIdx.x * 16 + quad * 4 + rr;
        if (row < n) {
          float v = oacc[nt][rr] + bv;
          if (col < 64) outM[(size_t)row * 64 + col] = v;
          else          outV[(size_t)row * 64 + (col - 64)] = v;
        }
      }
    }
  }
}

// ---------------------------------------------------------------- launch
extern "C" void kernel_launch(void* const* d_in, const int* in_sizes, int n_in,
                              void* d_out, int out_size, void* d_ws, size_t ws_size,
                              hipStream_t stream) {
  const float* x        = (const float*)d_in[0];
  const int*   edge_row = (const int*)d_in[1];
  const int*   edge_col = (const int*)d_in[2];
  const float* edge_val = (const float*)d_in[3];
  const float* W_gc0 = (const float*)d_in[4];
  const float* b_gc0 = (const float*)d_in[5];
  const float* W_gc1 = (const float*)d_in[6];
  const float* b_gc1 = (const float*)d_in[7];
  const float* Wm1 = (const float*)d_in[8];
  const float* bm1 = (const float*)d_in[9];
  const float* Wm2 = (const float*)d_in[10];
  const float* bm2 = (const float*)d_in[11];
  const float* Wv1 = (const float*)d_in[12];
  const float* bv1 = (const float*)d_in[13];
  const float* Wv2 = (const float*)d_in[14];
  const float* bv2 = (const float*)d_in[15];

  const int N = in_sizes[0] / 128;   // 50000
  const int E = in_sizes[1];         // 800000
  const int NBK = (N + RB - 1) / RB; // buckets (391)

  // workspace layout
  char* ws = (char*)d_ws;
  _Float16* bufA16 = (_Float16*)(ws);                            // N*128 f16 (support1)
  _Float16* bufB16 = (_Float16*)(ws + (size_t)N * 256);          // N*128 f16 (support2)
  int2*  s_pack = (int2*)(ws + (size_t)N * 512);                 // E*8
  char*  p = ws + (size_t)N * 512 + (size_t)E * 8;
  int*   row_ptr = (int*)p;           p += 200064;
  int*   bcur    = (int*)p;           p += (size_t)NBK * 64;     // 64B-padded counters
  uint2* bbuf    = (uint2*)p;         p += (size_t)NBK * BCAP * 8;  // ~8 MB
  _Float16* W0s  = (_Float16*)p;      p += 32768;
  _Float16* W1s  = (_Float16*)p;      p += 32768;
  _Float16* Wh1s = (_Float16*)p;      p += 32768;
  _Float16* Wh2s = (_Float16*)p;      p += 32768;

  float* out_mean = (float*)d_out;
  float* out_lvar = out_mean + (size_t)N * 64;

  // ---- build: binning || weight swizzle
  hipMemsetAsync(bcur, 0, (size_t)NBK * 64, stream);
  const int binBlocks = (E + CHUNK - 1) / CHUNK;   // 196
  buildA_kernel<<<binBlocks + 256, 256, 0, stream>>>(
      edge_row, edge_col, edge_val, bcur, bbuf, E, binBlocks,
      W_gc0, W_gc1, Wm1, Wv1, Wm2, Wv2, W0s, W1s, Wh1s, Wh2s);

  const int GB = (N + 127) / 128;  // gemm blocks (391)
  const int SB = (N + 15) / 16;    // spmm blocks (3125)

  // ---- CSR flush (fused bucket-base prefix) || support1 = x@W0
  buildB_kernel<<<NBK + GB, 256, 0, stream>>>(bbuf, bcur, row_ptr, s_pack,
                                              NBK, N, E, x, W0s, bufA16);
  // ---- fused: h1 = relu(agg(support1)+b0); support2 = h1@W1
  spmm_fused<false><<<SB, 256, 0, stream>>>((const half8*)bufA16, row_ptr, s_pack,
                                            b_gc0, W1s, nullptr,
                                            nullptr, nullptr, nullptr, nullptr,
                                            bufB16, nullptr, nullptr, N);
  // ---- fused: h2 = relu(agg(support2)+b1); t = relu(h2@Wh1+[bm1|bv1]);
  //             out = t@Wh2 + [bm2|bv2], split
  spmm_fused<true><<<SB, 256, 0, stream>>>((const half8*)bufB16, row_ptr, s_pack,
                                           b_gc1, Wh1s, Wh2s,
                                           bm1, bv1, bm2, bv2,
                                           nullptr, out_mean, out_lvar, N);
}

// Round 11
// 203.772 us; speedup vs baseline: 1.0704x; 1.0704x over previous
//
#include <hip/hip_runtime.h>
#include <type_traits>

// GCNEncoder: h1 = relu(SpMM(x@W0) + b0); h2 = relu(SpMM(h1@W1) + b1)
// mean = relu(h2@Wm1+bm1)@Wm2+bm2 ; logvar = relu(h2@Wv1+bv1)@Wv2+bv2
// R5: f16 pipeline, MFMA GEMMs. R7: block-local two-pass binning.
// R8: fused heads, fp32-A GEMM, half8 SpMM. R10: GEMM 2 A-frags/wave.
// R11 (FAILED +26): feature-chunked SpMM — line granularity + XCD replication.
// R12 (FAILED +11): bundled {unroll8, NT hints, fused build}.
// R13 (WIN -32.7, 218.9us): fused row-local GEMMs into spmm blocks.
// R14 (FAILED +13.7): degree-balanced rperm — serial tail + sort overhead.
// R15 (WIN -6.1, 212.8us): buildA || wconv; buildB || gemm-L1.
// R16 (FAILED +40.8): per-row col sort — no spmm gain (decoherence).
// R17 (FAILED +24.7): unroll8+NT gather — gather is L2-miss-BW-bound;
//      spmm ~41us each is near its structural floor (FETCH ~= compulsory).
// R18 (WIN -2.6, 210.2us): bscan fused into buildB; single-pass reg binning.
// R19 (FAILED +7.9): LDS bucket-sort staging + linear flush — lost the
//      single-pass reg binning, 40KB LDS cut co-residency (also for wconv),
//      extra scan+scatter passes outweighed the coalescing win. Reverted.
// R20: R18 exactly + buildA widened: 512-thread blocks, CHUNK 4096, still
//      8 edges/thread in regs. Halves reservation atomics (152K->77K),
//      doubles bbuf run length (5.2->10.5 edges), halves binning blocks.
//      No new passes, no extra LDS. wconv tail: 128 blocks of 512.

typedef _Float16 half8 __attribute__((ext_vector_type(8)));
typedef float floatx4 __attribute__((ext_vector_type(4)));

#define BCAP 2560   // bucket capacity; mean 2048, sigma ~45 -> +11 sigma
#define CHUNK 4096  // edges per binning block (512 thr x 8 edges)
#define RB 128      // rows per bucket
#define NBKMAX 392

// ---------------------------------------------------------------- gemm L1 (device)
// support1 = x(f32)@W0swz -> f16. R10 structure: 4 waves x 2 A-frags (32 rows),
// NT=8, KS=4. Wswz frag order [(ks*8+nt)*64+lane]*8+j, k=ks*32+quad*8+j,
// n=nt*16+(lane&15). C/D: col=lane&15, row=quad*4+reg (m89-verified).
__device__ void gemm_l1(int bid, const float* __restrict__ A,
                        const _Float16* __restrict__ Wswz,
                        _Float16* __restrict__ C0, int n) {
  const int t = threadIdx.x;
  const int lane = t & 63, wave = t >> 6;
  const int quad = lane >> 4, l16 = lane & 15;
  const int r_base = bid * 128 + wave * 32;

  int arow0 = r_base + l16;
  int arow1 = r_base + 16 + l16;
  if (arow0 >= n) arow0 = n - 1;        // clamp; clamped rows never stored
  if (arow1 >= n) arow1 = n - 1;
  const float* Ap0 = A + (size_t)arow0 * 128 + quad * 8;
  const float* Ap1 = A + (size_t)arow1 * 128 + quad * 8;

  floatx4 acc[2][8] = {};

#pragma unroll
  for (int ks = 0; ks < 4; ++ks) {
    float4 u = *(const float4*)(Ap0 + ks * 32);
    float4 w = *(const float4*)(Ap0 + ks * 32 + 4);
    half8 a0 = half8{(_Float16)u.x, (_Float16)u.y, (_Float16)u.z, (_Float16)u.w,
                     (_Float16)w.x, (_Float16)w.y, (_Float16)w.z, (_Float16)w.w};
    float4 u1 = *(const float4*)(Ap1 + ks * 32);
    float4 w1 = *(const float4*)(Ap1 + ks * 32 + 4);
    half8 a1 = half8{(_Float16)u1.x, (_Float16)u1.y, (_Float16)u1.z, (_Float16)u1.w,
                     (_Float16)w1.x, (_Float16)w1.y, (_Float16)w1.z, (_Float16)w1.w};
#pragma unroll
    for (int nt = 0; nt < 8; ++nt) {
      half8 b = *(const half8*)(Wswz + ((size_t)(ks * 8 + nt) * 64 + lane) * 8);
      acc[0][nt] = __builtin_amdgcn_mfma_f32_16x16x32_f16(a0, b, acc[0][nt], 0, 0, 0);
      acc[1][nt] = __builtin_amdgcn_mfma_f32_16x16x32_f16(a1, b, acc[1][nt], 0, 0, 0);
    }
  }

#pragma unroll
  for (int h = 0; h < 2; ++h) {
#pragma unroll
    for (int nt = 0; nt < 8; ++nt) {
      const int col = nt * 16 + l16;
#pragma unroll
      for (int r = 0; r < 4; ++r) {
        int row = r_base + h * 16 + quad * 4 + r;
        if (row < n) C0[(size_t)row * 128 + col] = (_Float16)acc[h][nt][r];
      }
    }
  }
}

// ---------------------------------------------------------------- buildA (512 thr)
// Blocks [0, binBlocks): single-pass block-local binning (8 edges/thread in
// regs: hist -> reserve -> scatter). Blocks [binBlocks, binBlocks+128):
// weight swizzle (4 segs, 512 thr each).
__global__ __launch_bounds__(512)
void buildA_kernel(const int* __restrict__ rows, const int* __restrict__ cols,
                   const float* __restrict__ vals,
                   int* __restrict__ bcur, uint2* __restrict__ bbuf, int e,
                   int binBlocks,
                   const float* __restrict__ w0, const float* __restrict__ w1,
                   const float* __restrict__ wm1, const float* __restrict__ wv1,
                   const float* __restrict__ wm2, const float* __restrict__ wv2,
                   _Float16* __restrict__ d0, _Float16* __restrict__ d1,
                   _Float16* __restrict__ dh1, _Float16* __restrict__ dh2) {
  __shared__ int cnt[NBKMAX];
  __shared__ int cur[NBKMAX];
  const int t = threadIdx.x;

  if (blockIdx.x >= binBlocks) {
    // ---- weight conversion (swizzle to MFMA fragment order)
    int i = (blockIdx.x - binBlocks) * 512 + t;
    if (i >= 65536) return;
    int seg = i >> 14, li = i & 16383;
    int j = li & 7, lane = (li >> 3) & 63, tt = li >> 9;
    int nt = tt & 7, ks = tt >> 3;         // NT=8, KS=4
    int k = ks * 32 + (lane >> 4) * 8 + j;
    int nn = nt * 16 + (lane & 15);
    float v;
    if (seg == 0)      v = w0[k * 128 + nn];
    else if (seg == 1) v = w1[k * 128 + nn];
    else if (seg == 2) v = (nn < 64) ? wm1[k * 64 + nn] : wv1[k * 64 + (nn - 64)];
    else v = (k < 64 && nn < 64) ? wm2[k * 64 + nn]
           : (k >= 64 && nn >= 64) ? wv2[(k - 64) * 64 + (nn - 64)] : 0.f;
    _Float16* dst = (seg == 0) ? d0 : (seg == 1) ? d1 : (seg == 2) ? dh1 : dh2;
    dst[li] = (_Float16)v;
    return;
  }

  // ---- single-pass block-local binning (CHUNK/512 = 8 edges per thread)
  const int lo = blockIdx.x * CHUNK, hi = min(lo + CHUNK, e);
  int myr[8], myc[8];
  float myv[8];
  int nk = 0;
  for (int i = lo + t; i < hi; i += 512, ++nk) {
    myr[nk] = rows[i];
    myc[nk] = cols[i];
    myv[nk] = vals[i];
  }
  for (int j = t; j < NBKMAX; j += 512) cnt[j] = 0;
  __syncthreads();
  for (int k = 0; k < nk; ++k)
    atomicAdd(&cnt[myr[k] >> 7], 1);
  __syncthreads();
  for (int j = t; j < NBKMAX; j += 512)
    if (cnt[j] > 0) cur[j] = atomicAdd(&bcur[j * 16], cnt[j]);
  __syncthreads();
  for (int k = 0; k < nk; ++k) {
    int r = myr[k];
    int b = r >> 7;
    int p = atomicAdd(&cur[b], 1);
    if (p < BCAP)
      bbuf[(size_t)b * BCAP + p] =
          make_uint2(((unsigned)(r & (RB - 1)) << 16) | (unsigned)myc[k],
                     __float_as_uint(myv[k]));
  }
}

// ---------------------------------------------------------------- buildB
// Blocks [0, nbk): bucketB — fused bucket-base prefix (over bcur), per-bucket
// LDS hist+scan -> row_ptr; LDS-staged coalesced CSR flush (~22.5 KB LDS).
// Blocks [nbk, nbk+GB): gemm_l1 — support1 = x@W0 (independent; overlaps).
__global__ __launch_bounds__(256)
void buildB_kernel(const uint2* __restrict__ bbuf, const int* __restrict__ bcur,
                   int* __restrict__ row_ptr, int2* __restrict__ s_pack,
                   int nbk, int n, int e_total,
                   const float* __restrict__ x, const _Float16* __restrict__ W0s,
                   _Float16* __restrict__ sup) {
  __shared__ int cnt[RB];
  __shared__ int scn[RB];
  __shared__ int red[256];
  __shared__ int2 stage[BCAP];

  if (blockIdx.x >= nbk) {
    gemm_l1(blockIdx.x - nbk, x, W0s, sup, n);
    return;
  }

  const int b = blockIdx.x, t = threadIdx.x;

  // fused exclusive prefix over bucket counts (nbk <= 512 -> <=2 loads/thread)
  int partial = 0;
  for (int j = t; j < b; j += 256) partial += bcur[j * 16];
  red[t] = partial;
  __syncthreads();
#pragma unroll
  for (int off = 128; off > 0; off >>= 1) {
    if (t < off) red[t] += red[t + off];
    __syncthreads();
  }
  const int base = red[0];

  const int e = min(bcur[b * 16], BCAP);
  const uint2* src = bbuf + (size_t)b * BCAP;

  if (t < RB) cnt[t] = 0;
  __syncthreads();
  for (int i = t; i < e; i += 256)
    atomicAdd(&cnt[(src[i].x >> 16) & (RB - 1)], 1);
  __syncthreads();
  int c = (t < RB) ? cnt[t] : 0;
  if (t < RB) scn[t] = c;
  __syncthreads();
#pragma unroll
  for (int off = 1; off < RB; off <<= 1) {
    int a = (t >= off && t < RB) ? scn[t - off] : 0;
    __syncthreads();
    if (t < RB) scn[t] += a;
    __syncthreads();
  }
  if (t < RB) {
    int excl = scn[t] - c;
    int grow = b * RB + t;
    if (grow < n) row_ptr[grow] = base + excl;
    cnt[t] = excl;   // becomes per-row cursor
  }
  if (b == 0 && t == 0) row_ptr[n] = e_total;
  __syncthreads();
  for (int i = t; i < e; i += 256) {
    uint2 u = src[i];
    int pos = atomicAdd(&cnt[(u.x >> 16) & (RB - 1)], 1);
    stage[pos] = make_int2((int)(u.x & 0xFFFFu), (int)u.y);
  }
  __syncthreads();
  for (int i = t; i < e; i += 256)
    s_pack[base + i] = stage[i];
}

// ---------------------------------------------------------------- fused SpMM+GEMM
// Phase 1 (R10 gather core): 16 lanes/row, half8/lane, 16 rows/block,
// unroll 4, plain loads. h = relu(agg + gbias) -> LDS (padded 136) -> MFMA
// vs swizzled weights (A-frag pattern identical to gemm16, m89-verified).
// HEADS=false: emit support2 = h@W1swz. HEADS=true: t = relu(h@W1swz+[hb]),
// out = t@W2swz+[ob], split fp32 stores.
template<bool HEADS>
__global__ __launch_bounds__(256)
void spmm_fused(const half8* __restrict__ sup, const int* __restrict__ row_ptr,
                const int2* __restrict__ s_pack, const float* __restrict__ gbias,
                const _Float16* __restrict__ W1swz, const _Float16* __restrict__ W2swz,
                const float* __restrict__ hb0, const float* __restrict__ hb1,
                const float* __restrict__ ob0, const float* __restrict__ ob1,
                _Float16* __restrict__ outA, float* __restrict__ outM,
                float* __restrict__ outV, int n) {
  __shared__ _Float16 hs[16][136];
  __shared__ _Float16 ts[HEADS ? 16 : 1][136];
  const int t = threadIdx.x;
  const int g = t >> 4;
  const int l = t & 15;                 // feats [8l, 8l+8)
  int r = blockIdx.x * 16 + g;
  if (r >= n) r = n - 1;                // N%16==0 in practice; stores guarded
  const int beg = row_ptr[r], end = row_ptr[r + 1];

  // ---- gather
  float acc[8] = {};
  int i = beg;
  for (; i + 3 < end; i += 4) {
    int2 e0 = s_pack[i], e1 = s_pack[i + 1], e2 = s_pack[i + 2], e3 = s_pack[i + 3];
    half8 g0 = sup[(size_t)e0.x * 16 + l];
    half8 g1 = sup[(size_t)e1.x * 16 + l];
    half8 g2 = sup[(size_t)e2.x * 16 + l];
    half8 g3 = sup[(size_t)e3.x * 16 + l];
    float v0 = __int_as_float(e0.y), v1 = __int_as_float(e1.y);
    float v2 = __int_as_float(e2.y), v3 = __int_as_float(e3.y);
#pragma unroll
    for (int jj = 0; jj < 8; ++jj) acc[jj] = fmaf(v0, (float)g0[jj], acc[jj]);
#pragma unroll
    for (int jj = 0; jj < 8; ++jj) acc[jj] = fmaf(v1, (float)g1[jj], acc[jj]);
#pragma unroll
    for (int jj = 0; jj < 8; ++jj) acc[jj] = fmaf(v2, (float)g2[jj], acc[jj]);
#pragma unroll
    for (int jj = 0; jj < 8; ++jj) acc[jj] = fmaf(v3, (float)g3[jj], acc[jj]);
  }
  for (; i < end; ++i) {
    int2 e0 = s_pack[i];
    float v = __int_as_float(e0.y);
    half8 gg = sup[(size_t)e0.x * 16 + l];
#pragma unroll
    for (int jj = 0; jj < 8; ++jj) acc[jj] = fmaf(v, (float)gg[jj], acc[jj]);
  }

  // ---- h = relu(acc + gbias) -> LDS tile
  float4 b0 = *(const float4*)(gbias + 8 * l);
  float4 b1 = *(const float4*)(gbias + 8 * l + 4);
  _Float16* hp = &hs[g][8 * l];
  hp[0] = (_Float16)fmaxf(acc[0] + b0.x, 0.f);
  hp[1] = (_Float16)fmaxf(acc[1] + b0.y, 0.f);
  hp[2] = (_Float16)fmaxf(acc[2] + b0.z, 0.f);
  hp[3] = (_Float16)fmaxf(acc[3] + b0.w, 0.f);
  hp[4] = (_Float16)fmaxf(acc[4] + b1.x, 0.f);
  hp[5] = (_Float16)fmaxf(acc[5] + b1.y, 0.f);
  hp[6] = (_Float16)fmaxf(acc[6] + b1.z, 0.f);
  hp[7] = (_Float16)fmaxf(acc[7] + b1.w, 0.f);
  __syncthreads();

  // ---- MFMA phase: wave handles cols [wave*32, wave*32+32)
  const int lane = t & 63, wave = t >> 6;
  const int quad = lane >> 4, l16 = lane & 15;
  floatx4 cacc[2] = {{0.f, 0.f, 0.f, 0.f}, {0.f, 0.f, 0.f, 0.f}};
#pragma unroll
  for (int ks = 0; ks < 4; ++ks) {
    half8 a = *(const half8*)&hs[l16][ks * 32 + quad * 8];
#pragma unroll
    for (int nt = 0; nt < 2; ++nt) {
      int ntg = wave * 2 + nt;
      half8 b = *(const half8*)(W1swz + ((size_t)(ks * 8 + ntg) * 64 + lane) * 8);
      cacc[nt] = __builtin_amdgcn_mfma_f32_16x16x32_f16(a, b, cacc[nt], 0, 0, 0);
    }
  }

  if constexpr (!HEADS) {
#pragma unroll
    for (int nt = 0; nt < 2; ++nt) {
      int col = wave * 32 + nt * 16 + l16;
#pragma unroll
      for (int rr = 0; rr < 4; ++rr) {
        int row = blockIdx.x * 16 + quad * 4 + rr;
        if (row < n) outA[(size_t)row * 128 + col] = (_Float16)cacc[nt][rr];
      }
    }
  } else {
#pragma unroll
    for (int nt = 0; nt < 2; ++nt) {
      int col = wave * 32 + nt * 16 + l16;
      float bv = (col < 64) ? hb0[col] : hb1[col - 64];
#pragma unroll
      for (int rr = 0; rr < 4; ++rr)
        ts[quad * 4 + rr][col] = (_Float16)fmaxf(cacc[nt][rr] + bv, 0.f);
    }
    __syncthreads();
    floatx4 oacc[2] = {{0.f, 0.f, 0.f, 0.f}, {0.f, 0.f, 0.f, 0.f}};
#pragma unroll
    for (int ks = 0; ks < 4; ++ks) {
      half8 a = *(const half8*)&ts[l16][ks * 32 + quad * 8];
#pragma unroll
      for (int nt = 0; nt < 2; ++nt) {
        int ntg = wave * 2 + nt;
        half8 b = *(const half8*)(W2swz + ((size_t)(ks * 8 + ntg) * 64 + lane) * 8);
        oacc[nt] = __builtin_amdgcn_mfma_f32_16x16x32_f16(a, b, oacc[nt], 0, 0, 0);
      }
    }
#pragma unroll
    for (int nt = 0; nt < 2; ++nt) {
      int col = wave * 32 + nt * 16 + l16;
      float bv = (col < 64) ? ob0[col] : ob1[col - 64];
#pragma unroll
      for (int rr = 0; rr < 4; ++rr) {
        int row = blockIdx.x * 16 + quad * 4 + rr;
        if (row < n) {
          float v = oacc[nt][rr] + bv;
          if (col < 64) outM[(size_t)row * 64 + col] = v;
          else          outV[(size_t)row * 64 + (col - 64)] = v;
        }
      }
    }
  }
}

// ---------------------------------------------------------------- launch
extern "C" void kernel_launch(void* const* d_in, const int* in_sizes, int n_in,
                              void* d_out, int out_size, void* d_ws, size_t ws_size,
                              hipStream_t stream) {
  const float* x        = (const float*)d_in[0];
  const int*   edge_row = (const int*)d_in[1];
  const int*   edge_col = (const int*)d_in[2];
  const float* edge_val = (const float*)d_in[3];
  const float* W_gc0 = (const float*)d_in[4];
  const float* b_gc0 = (const float*)d_in[5];
  const float* W_gc1 = (const float*)d_in[6];
  const float* b_gc1 = (const float*)d_in[7];
  const float* Wm1 = (const float*)d_in[8];
  const float* bm1 = (const float*)d_in[9];
  const float* Wm2 = (const float*)d_in[10];
  const float* bm2 = (const float*)d_in[11];
  const float* Wv1 = (const float*)d_in[12];
  const float* bv1 = (const float*)d_in[13];
  const float* Wv2 = (const float*)d_in[14];
  const float* bv2 = (const float*)d_in[15];

  const int N = in_sizes[0] / 128;   // 50000
  const int E = in_sizes[1];         // 800000
  const int NBK = (N + RB - 1) / RB; // buckets (391)

  // workspace layout
  char* ws = (char*)d_ws;
  _Float16* bufA16 = (_Float16*)(ws);                            // N*128 f16 (support1)
  _Float16* bufB16 = (_Float16*)(ws + (size_t)N * 256);          // N*128 f16 (support2)
  int2*  s_pack = (int2*)(ws + (size_t)N * 512);                 // E*8
  char*  p = ws + (size_t)N * 512 + (size_t)E * 8;
  int*   row_ptr = (int*)p;           p += 200064;
  int*   bcur    = (int*)p;           p += (size_t)NBK * 64;     // 64B-padded counters
  uint2* bbuf    = (uint2*)p;         p += (size_t)NBK * BCAP * 8;  // ~8 MB
  _Float16* W0s  = (_Float16*)p;      p += 32768;
  _Float16* W1s  = (_Float16*)p;      p += 32768;
  _Float16* Wh1s = (_Float16*)p;      p += 32768;
  _Float16* Wh2s = (_Float16*)p;      p += 32768;

  float* out_mean = (float*)d_out;
  float* out_lvar = out_mean + (size_t)N * 64;

  // ---- build: binning || weight swizzle (512-thread blocks)
  hipMemsetAsync(bcur, 0, (size_t)NBK * 64, stream);
  const int binBlocks = (E + CHUNK - 1) / CHUNK;   // 196
  buildA_kernel<<<binBlocks + 128, 512, 0, stream>>>(
      edge_row, edge_col, edge_val, bcur, bbuf, E, binBlocks,
      W_gc0, W_gc1, Wm1, Wv1, Wm2, Wv2, W0s, W1s, Wh1s, Wh2s);

  const int GB = (N + 127) / 128;  // gemm blocks (391)
  const int SB = (N + 15) / 16;    // spmm blocks (3125)

  // ---- CSR flush (fused bucket-base prefix) || support1 = x@W0
  buildB_kernel<<<NBK + GB, 256, 0, stream>>>(bbuf, bcur, row_ptr, s_pack,
                                              NBK, N, E, x, W0s, bufA16);
  // ---- fused: h1 = relu(agg(support1)+b0); support2 = h1@W1
  spmm_fused<false><<<SB, 256, 0, stream>>>((const half8*)bufA16, row_ptr, s_pack,
                                            b_gc0, W1s, nullptr,
                                            nullptr, nullptr, nullptr, nullptr,
                                            bufB16, nullptr, nullptr, N);
  // ---- fused: h2 = relu(agg(support2)+b1); t = relu(h2@Wh1+[bm1|bv1]);
  //             out = t@Wh2 + [bm2|bv2], split
  spmm_fused<true><<<SB, 256, 0, stream>>>((const half8*)bufB16, row_ptr, s_pack,
                                           b_gc1, Wh1s, Wh2s,
                                           bm1, bv1, bm2, bv2,
                                           nullptr, out_mean, out_lvar, N);
}

// Round 12
// 200.313 us; speedup vs baseline: 1.0889x; 1.0173x over previous
//
#include <hip/hip_runtime.h>
#include <type_traits>

// GCNEncoder: h1 = relu(SpMM(x@W0) + b0); h2 = relu(SpMM(h1@W1) + b1)
// mean = relu(h2@Wm1+bm1)@Wm2+bm2 ; logvar = relu(h2@Wv1+bv1)@Wv2+bv2
// R5: f16 pipeline, MFMA GEMMs. R7: block-local two-pass binning.
// R8: fused heads, fp32-A GEMM, half8 SpMM. R10: GEMM 2 A-frags/wave.
// R11 (FAILED +26): feature-chunked SpMM — line granularity + XCD replication.
// R12 (FAILED +11): bundled {unroll8, NT hints, fused build}.
// R13 (WIN -32.7, 218.9us): fused row-local GEMMs into spmm blocks.
// R14 (FAILED +13.7): degree-balanced rperm — serial tail + sort overhead.
// R15 (WIN -6.1, 212.8us): buildA || wconv; buildB || gemm-L1.
// R16 (FAILED +40.8): per-row col sort — no spmm gain (decoherence).
// R17 (FAILED +24.7): unroll8+NT gather — gather is L2-miss-BW-bound;
//      spmm ~41us each is near its structural floor (FETCH ~= compulsory).
// R18 (WIN -2.6, 210.2us): bscan fused into buildB; single-pass reg binning.
// R19 (FAILED +7.9): LDS bucket-sort staging — lost single-pass binning,
//      40KB LDS cut co-residency, extra passes outweighed coalescing.
// R20 (WIN -6.4, 203.8us): buildA widened to 512thr/CHUNK 4096 — confirms
//      cost = shared-resource terms (reservation atomics + partial-line runs),
//      not per-block latency.
// R21: one more doubling: CHUNK 8192 (512thr x 16 edges/thread, compile-time
//      unrolled predicated regs — rule #20). Atomics 77K->38K; run length
//      10.5->21 edges = 168B, crossing the 128B line threshold (scatter
//      becomes mostly full-line writes). Binning blocks 196->98.

typedef _Float16 half8 __attribute__((ext_vector_type(8)));
typedef float floatx4 __attribute__((ext_vector_type(4)));

#define BCAP 2560   // bucket capacity; mean 2048, sigma ~45 -> +11 sigma
#define CHUNK 8192  // edges per binning block (512 thr x 16 edges)
#define RB 128      // rows per bucket
#define NBKMAX 392

// ---------------------------------------------------------------- gemm L1 (device)
// support1 = x(f32)@W0swz -> f16. R10 structure: 4 waves x 2 A-frags (32 rows),
// NT=8, KS=4. Wswz frag order [(ks*8+nt)*64+lane]*8+j, k=ks*32+quad*8+j,
// n=nt*16+(lane&15). C/D: col=lane&15, row=quad*4+reg (m89-verified).
__device__ void gemm_l1(int bid, const float* __restrict__ A,
                        const _Float16* __restrict__ Wswz,
                        _Float16* __restrict__ C0, int n) {
  const int t = threadIdx.x;
  const int lane = t & 63, wave = t >> 6;
  const int quad = lane >> 4, l16 = lane & 15;
  const int r_base = bid * 128 + wave * 32;

  int arow0 = r_base + l16;
  int arow1 = r_base + 16 + l16;
  if (arow0 >= n) arow0 = n - 1;        // clamp; clamped rows never stored
  if (arow1 >= n) arow1 = n - 1;
  const float* Ap0 = A + (size_t)arow0 * 128 + quad * 8;
  const float* Ap1 = A + (size_t)arow1 * 128 + quad * 8;

  floatx4 acc[2][8] = {};

#pragma unroll
  for (int ks = 0; ks < 4; ++ks) {
    float4 u = *(const float4*)(Ap0 + ks * 32);
    float4 w = *(const float4*)(Ap0 + ks * 32 + 4);
    half8 a0 = half8{(_Float16)u.x, (_Float16)u.y, (_Float16)u.z, (_Float16)u.w,
                     (_Float16)w.x, (_Float16)w.y, (_Float16)w.z, (_Float16)w.w};
    float4 u1 = *(const float4*)(Ap1 + ks * 32);
    float4 w1 = *(const float4*)(Ap1 + ks * 32 + 4);
    half8 a1 = half8{(_Float16)u1.x, (_Float16)u1.y, (_Float16)u1.z, (_Float16)u1.w,
                     (_Float16)w1.x, (_Float16)w1.y, (_Float16)w1.z, (_Float16)w1.w};
#pragma unroll
    for (int nt = 0; nt < 8; ++nt) {
      half8 b = *(const half8*)(Wswz + ((size_t)(ks * 8 + nt) * 64 + lane) * 8);
      acc[0][nt] = __builtin_amdgcn_mfma_f32_16x16x32_f16(a0, b, acc[0][nt], 0, 0, 0);
      acc[1][nt] = __builtin_amdgcn_mfma_f32_16x16x32_f16(a1, b, acc[1][nt], 0, 0, 0);
    }
  }

#pragma unroll
  for (int h = 0; h < 2; ++h) {
#pragma unroll
    for (int nt = 0; nt < 8; ++nt) {
      const int col = nt * 16 + l16;
#pragma unroll
      for (int r = 0; r < 4; ++r) {
        int row = r_base + h * 16 + quad * 4 + r;
        if (row < n) C0[(size_t)row * 128 + col] = (_Float16)acc[h][nt][r];
      }
    }
  }
}

// ---------------------------------------------------------------- buildA (512 thr)
// Blocks [0, binBlocks): single-pass block-local binning, 16 edges/thread in
// registers (compile-time unrolled, predicated). Blocks [binBlocks, +128):
// weight swizzle (4 segs, 512 thr each).
__global__ __launch_bounds__(512)
void buildA_kernel(const int* __restrict__ rows, const int* __restrict__ cols,
                   const float* __restrict__ vals,
                   int* __restrict__ bcur, uint2* __restrict__ bbuf, int e,
                   int binBlocks,
                   const float* __restrict__ w0, const float* __restrict__ w1,
                   const float* __restrict__ wm1, const float* __restrict__ wv1,
                   const float* __restrict__ wm2, const float* __restrict__ wv2,
                   _Float16* __restrict__ d0, _Float16* __restrict__ d1,
                   _Float16* __restrict__ dh1, _Float16* __restrict__ dh2) {
  __shared__ int cnt[NBKMAX];
  __shared__ int cur[NBKMAX];
  const int t = threadIdx.x;

  if (blockIdx.x >= binBlocks) {
    // ---- weight conversion (swizzle to MFMA fragment order)
    int i = (blockIdx.x - binBlocks) * 512 + t;
    if (i >= 65536) return;
    int seg = i >> 14, li = i & 16383;
    int j = li & 7, lane = (li >> 3) & 63, tt = li >> 9;
    int nt = tt & 7, ks = tt >> 3;         // NT=8, KS=4
    int k = ks * 32 + (lane >> 4) * 8 + j;
    int nn = nt * 16 + (lane & 15);
    float v;
    if (seg == 0)      v = w0[k * 128 + nn];
    else if (seg == 1) v = w1[k * 128 + nn];
    else if (seg == 2) v = (nn < 64) ? wm1[k * 64 + nn] : wv1[k * 64 + (nn - 64)];
    else v = (k < 64 && nn < 64) ? wm2[k * 64 + nn]
           : (k >= 64 && nn >= 64) ? wv2[(k - 64) * 64 + (nn - 64)] : 0.f;
    _Float16* dst = (seg == 0) ? d0 : (seg == 1) ? d1 : (seg == 2) ? dh1 : dh2;
    dst[li] = (_Float16)v;
    return;
  }

  // ---- single-pass block-local binning (16 edges/thread, all reg-resident)
  const int lo = blockIdx.x * CHUNK, hi = min(lo + CHUNK, e);
  int myr[16], myc[16];
  float myv[16];
#pragma unroll
  for (int k = 0; k < 16; ++k) {
    int i = lo + t + k * 512;
    bool valid = (i < hi);
    myr[k] = valid ? rows[i] : -1;       // -1 sentinel: skipped below
    myc[k] = valid ? cols[i] : 0;
    myv[k] = valid ? vals[i] : 0.f;
  }
  for (int j = t; j < NBKMAX; j += 512) cnt[j] = 0;
  __syncthreads();
#pragma unroll
  for (int k = 0; k < 16; ++k)
    if (myr[k] >= 0) atomicAdd(&cnt[myr[k] >> 7], 1);
  __syncthreads();
  for (int j = t; j < NBKMAX; j += 512)
    if (cnt[j] > 0) cur[j] = atomicAdd(&bcur[j * 16], cnt[j]);
  __syncthreads();
#pragma unroll
  for (int k = 0; k < 16; ++k) {
    int r = myr[k];
    if (r >= 0) {
      int b = r >> 7;
      int p = atomicAdd(&cur[b], 1);
      if (p < BCAP)
        bbuf[(size_t)b * BCAP + p] =
            make_uint2(((unsigned)(r & (RB - 1)) << 16) | (unsigned)myc[k],
                       __float_as_uint(myv[k]));
    }
  }
}

// ---------------------------------------------------------------- buildB
// Blocks [0, nbk): bucketB — fused bucket-base prefix (over bcur), per-bucket
// LDS hist+scan -> row_ptr; LDS-staged coalesced CSR flush (~22.5 KB LDS).
// Blocks [nbk, nbk+GB): gemm_l1 — support1 = x@W0 (independent; overlaps).
__global__ __launch_bounds__(256)
void buildB_kernel(const uint2* __restrict__ bbuf, const int* __restrict__ bcur,
                   int* __restrict__ row_ptr, int2* __restrict__ s_pack,
                   int nbk, int n, int e_total,
                   const float* __restrict__ x, const _Float16* __restrict__ W0s,
                   _Float16* __restrict__ sup) {
  __shared__ int cnt[RB];
  __shared__ int scn[RB];
  __shared__ int red[256];
  __shared__ int2 stage[BCAP];

  if (blockIdx.x >= nbk) {
    gemm_l1(blockIdx.x - nbk, x, W0s, sup, n);
    return;
  }

  const int b = blockIdx.x, t = threadIdx.x;

  // fused exclusive prefix over bucket counts (nbk <= 512 -> <=2 loads/thread)
  int partial = 0;
  for (int j = t; j < b; j += 256) partial += bcur[j * 16];
  red[t] = partial;
  __syncthreads();
#pragma unroll
  for (int off = 128; off > 0; off >>= 1) {
    if (t < off) red[t] += red[t + off];
    __syncthreads();
  }
  const int base = red[0];

  const int e = min(bcur[b * 16], BCAP);
  const uint2* src = bbuf + (size_t)b * BCAP;

  if (t < RB) cnt[t] = 0;
  __syncthreads();
  for (int i = t; i < e; i += 256)
    atomicAdd(&cnt[(src[i].x >> 16) & (RB - 1)], 1);
  __syncthreads();
  int c = (t < RB) ? cnt[t] : 0;
  if (t < RB) scn[t] = c;
  __syncthreads();
#pragma unroll
  for (int off = 1; off < RB; off <<= 1) {
    int a = (t >= off && t < RB) ? scn[t - off] : 0;
    __syncthreads();
    if (t < RB) scn[t] += a;
    __syncthreads();
  }
  if (t < RB) {
    int excl = scn[t] - c;
    int grow = b * RB + t;
    if (grow < n) row_ptr[grow] = base + excl;
    cnt[t] = excl;   // becomes per-row cursor
  }
  if (b == 0 && t == 0) row_ptr[n] = e_total;
  __syncthreads();
  for (int i = t; i < e; i += 256) {
    uint2 u = src[i];
    int pos = atomicAdd(&cnt[(u.x >> 16) & (RB - 1)], 1);
    stage[pos] = make_int2((int)(u.x & 0xFFFFu), (int)u.y);
  }
  __syncthreads();
  for (int i = t; i < e; i += 256)
    s_pack[base + i] = stage[i];
}

// ---------------------------------------------------------------- fused SpMM+GEMM
// Phase 1 (R10 gather core): 16 lanes/row, half8/lane, 16 rows/block,
// unroll 4, plain loads. h = relu(agg + gbias) -> LDS (padded 136) -> MFMA
// vs swizzled weights (A-frag pattern identical to gemm16, m89-verified).
// HEADS=false: emit support2 = h@W1swz. HEADS=true: t = relu(h@W1swz+[hb]),
// out = t@W2swz+[ob], split fp32 stores.
template<bool HEADS>
__global__ __launch_bounds__(256)
void spmm_fused(const half8* __restrict__ sup, const int* __restrict__ row_ptr,
                const int2* __restrict__ s_pack, const float* __restrict__ gbias,
                const _Float16* __restrict__ W1swz, const _Float16* __restrict__ W2swz,
                const float* __restrict__ hb0, const float* __restrict__ hb1,
                const float* __restrict__ ob0, const float* __restrict__ ob1,
                _Float16* __restrict__ outA, float* __restrict__ outM,
                float* __restrict__ outV, int n) {
  __shared__ _Float16 hs[16][136];
  __shared__ _Float16 ts[HEADS ? 16 : 1][136];
  const int t = threadIdx.x;
  const int g = t >> 4;
  const int l = t & 15;                 // feats [8l, 8l+8)
  int r = blockIdx.x * 16 + g;
  if (r >= n) r = n - 1;                // N%16==0 in practice; stores guarded
  const int beg = row_ptr[r], end = row_ptr[r + 1];

  // ---- gather
  float acc[8] = {};
  int i = beg;
  for (; i + 3 < end; i += 4) {
    int2 e0 = s_pack[i], e1 = s_pack[i + 1], e2 = s_pack[i + 2], e3 = s_pack[i + 3];
    half8 g0 = sup[(size_t)e0.x * 16 + l];
    half8 g1 = sup[(size_t)e1.x * 16 + l];
    half8 g2 = sup[(size_t)e2.x * 16 + l];
    half8 g3 = sup[(size_t)e3.x * 16 + l];
    float v0 = __int_as_float(e0.y), v1 = __int_as_float(e1.y);
    float v2 = __int_as_float(e2.y), v3 = __int_as_float(e3.y);
#pragma unroll
    for (int jj = 0; jj < 8; ++jj) acc[jj] = fmaf(v0, (float)g0[jj], acc[jj]);
#pragma unroll
    for (int jj = 0; jj < 8; ++jj) acc[jj] = fmaf(v1, (float)g1[jj], acc[jj]);
#pragma unroll
    for (int jj = 0; jj < 8; ++jj) acc[jj] = fmaf(v2, (float)g2[jj], acc[jj]);
#pragma unroll
    for (int jj = 0; jj < 8; ++jj) acc[jj] = fmaf(v3, (float)g3[jj], acc[jj]);
  }
  for (; i < end; ++i) {
    int2 e0 = s_pack[i];
    float v = __int_as_float(e0.y);
    half8 gg = sup[(size_t)e0.x * 16 + l];
#pragma unroll
    for (int jj = 0; jj < 8; ++jj) acc[jj] = fmaf(v, (float)gg[jj], acc[jj]);
  }

  // ---- h = relu(acc + gbias) -> LDS tile
  float4 b0 = *(const float4*)(gbias + 8 * l);
  float4 b1 = *(const float4*)(gbias + 8 * l + 4);
  _Float16* hp = &hs[g][8 * l];
  hp[0] = (_Float16)fmaxf(acc[0] + b0.x, 0.f);
  hp[1] = (_Float16)fmaxf(acc[1] + b0.y, 0.f);
  hp[2] = (_Float16)fmaxf(acc[2] + b0.z, 0.f);
  hp[3] = (_Float16)fmaxf(acc[3] + b0.w, 0.f);
  hp[4] = (_Float16)fmaxf(acc[4] + b1.x, 0.f);
  hp[5] = (_Float16)fmaxf(acc[5] + b1.y, 0.f);
  hp[6] = (_Float16)fmaxf(acc[6] + b1.z, 0.f);
  hp[7] = (_Float16)fmaxf(acc[7] + b1.w, 0.f);
  __syncthreads();

  // ---- MFMA phase: wave handles cols [wave*32, wave*32+32)
  const int lane = t & 63, wave = t >> 6;
  const int quad = lane >> 4, l16 = lane & 15;
  floatx4 cacc[2] = {{0.f, 0.f, 0.f, 0.f}, {0.f, 0.f, 0.f, 0.f}};
#pragma unroll
  for (int ks = 0; ks < 4; ++ks) {
    half8 a = *(const half8*)&hs[l16][ks * 32 + quad * 8];
#pragma unroll
    for (int nt = 0; nt < 2; ++nt) {
      int ntg = wave * 2 + nt;
      half8 b = *(const half8*)(W1swz + ((size_t)(ks * 8 + ntg) * 64 + lane) * 8);
      cacc[nt] = __builtin_amdgcn_mfma_f32_16x16x32_f16(a, b, cacc[nt], 0, 0, 0);
    }
  }

  if constexpr (!HEADS) {
#pragma unroll
    for (int nt = 0; nt < 2; ++nt) {
      int col = wave * 32 + nt * 16 + l16;
#pragma unroll
      for (int rr = 0; rr < 4; ++rr) {
        int row = blockIdx.x * 16 + quad * 4 + rr;
        if (row < n) outA[(size_t)row * 128 + col] = (_Float16)cacc[nt][rr];
      }
    }
  } else {
#pragma unroll
    for (int nt = 0; nt < 2; ++nt) {
      int col = wave * 32 + nt * 16 + l16;
      float bv = (col < 64) ? hb0[col] : hb1[col - 64];
#pragma unroll
      for (int rr = 0; rr < 4; ++rr)
        ts[quad * 4 + rr][col] = (_Float16)fmaxf(cacc[nt][rr] + bv, 0.f);
    }
    __syncthreads();
    floatx4 oacc[2] = {{0.f, 0.f, 0.f, 0.f}, {0.f, 0.f, 0.f, 0.f}};
#pragma unroll
    for (int ks = 0; ks < 4; ++ks) {
      half8 a = *(const half8*)&ts[l16][ks * 32 + quad * 8];
#pragma unroll
      for (int nt = 0; nt < 2; ++nt) {
        int ntg = wave * 2 + nt;
        half8 b = *(const half8*)(W2swz + ((size_t)(ks * 8 + ntg) * 64 + lane) * 8);
        oacc[nt] = __builtin_amdgcn_mfma_f32_16x16x32_f16(a, b, oacc[nt], 0, 0, 0);
      }
    }
#pragma unroll
    for (int nt = 0; nt < 2; ++nt) {
      int col = wave * 32 + nt * 16 + l16;
      float bv = (col < 64) ? ob0[col] : ob1[col - 64];
#pragma unroll
      for (int rr = 0; rr < 4; ++rr) {
        int row = blockIdx.x * 16 + quad * 4 + rr;
        if (row < n) {
          float v = oacc[nt][rr] + bv;
          if (col < 64) outM[(size_t)row * 64 + col] = v;
          else          outV[(size_t)row * 64 + (col - 64)] = v;
        }
      }
    }
  }
}

// ---------------------------------------------------------------- launch
extern "C" void kernel_launch(void* const* d_in, const int* in_sizes, int n_in,
                              void* d_out, int out_size, void* d_ws, size_t ws_size,
                              hipStream_t stream) {
  const float* x        = (const float*)d_in[0];
  const int*   edge_row = (const int*)d_in[1];
  const int*   edge_col = (const int*)d_in[2];
  const float* edge_val = (const float*)d_in[3];
  const float* W_gc0 = (const float*)d_in[4];
  const float* b_gc0 = (const float*)d_in[5];
  const float* W_gc1 = (const float*)d_in[6];
  const float* b_gc1 = (const float*)d_in[7];
  const float* Wm1 = (const float*)d_in[8];
  const float* bm1 = (const float*)d_in[9];
  const float* Wm2 = (const float*)d_in[10];
  const float* bm2 = (const float*)d_in[11];
  const float* Wv1 = (const float*)d_in[12];
  const float* bv1 = (const float*)d_in[13];
  const float* Wv2 = (const float*)d_in[14];
  const float* bv2 = (const float*)d_in[15];

  const int N = in_sizes[0] / 128;   // 50000
  const int E = in_sizes[1];         // 800000
  const int NBK = (N + RB - 1) / RB; // buckets (391)

  // workspace layout
  char* ws = (char*)d_ws;
  _Float16* bufA16 = (_Float16*)(ws);                            // N*128 f16 (support1)
  _Float16* bufB16 = (_Float16*)(ws + (size_t)N * 256);          // N*128 f16 (support2)
  int2*  s_pack = (int2*)(ws + (size_t)N * 512);                 // E*8
  char*  p = ws + (size_t)N * 512 + (size_t)E * 8;
  int*   row_ptr = (int*)p;           p += 200064;
  int*   bcur    = (int*)p;           p += (size_t)NBK * 64;     // 64B-padded counters
  uint2* bbuf    = (uint2*)p;         p += (size_t)NBK * BCAP * 8;  // ~8 MB
  _Float16* W0s  = (_Float16*)p;      p += 32768;
  _Float16* W1s  = (_Float16*)p;      p += 32768;
  _Float16* Wh1s = (_Float16*)p;      p += 32768;
  _Float16* Wh2s = (_Float16*)p;      p += 32768;

  float* out_mean = (float*)d_out;
  float* out_lvar = out_mean + (size_t)N * 64;

  // ---- build: binning || weight swizzle (512-thread blocks)
  hipMemsetAsync(bcur, 0, (size_t)NBK * 64, stream);
  const int binBlocks = (E + CHUNK - 1) / CHUNK;   // 98
  buildA_kernel<<<binBlocks + 128, 512, 0, stream>>>(
      edge_row, edge_col, edge_val, bcur, bbuf, E, binBlocks,
      W_gc0, W_gc1, Wm1, Wv1, Wm2, Wv2, W0s, W1s, Wh1s, Wh2s);

  const int GB = (N + 127) / 128;  // gemm blocks (391)
  const int SB = (N + 15) / 16;    // spmm blocks (3125)

  // ---- CSR flush (fused bucket-base prefix) || support1 = x@W0
  buildB_kernel<<<NBK + GB, 256, 0, stream>>>(bbuf, bcur, row_ptr, s_pack,
                                              NBK, N, E, x, W0s, bufA16);
  // ---- fused: h1 = relu(agg(support1)+b0); support2 = h1@W1
  spmm_fused<false><<<SB, 256, 0, stream>>>((const half8*)bufA16, row_ptr, s_pack,
                                            b_gc0, W1s, nullptr,
                                            nullptr, nullptr, nullptr, nullptr,
                                            bufB16, nullptr, nullptr, N);
  // ---- fused: h2 = relu(agg(support2)+b1); t = relu(h2@Wh1+[bm1|bv1]);
  //             out = t@Wh2 + [bm2|bv2], split
  spmm_fused<true><<<SB, 256, 0, stream>>>((const half8*)bufB16, row_ptr, s_pack,
                                           b_gc1, Wh1s, Wh2s,
                                           bm1, bv1, bm2, bv2,
                                           nullptr, out_mean, out_lvar, N);
}